// Round 3
// baseline (1620.265 us; speedup 1.0000x reference)
//
#include <hip/hip_runtime.h>
#include <stdint.h>

#define B      256
#define DIN    700
#define T      250
#define H      1024
#define DOUT   20
#define NW_IN  11     // u64 words for 700 input bits
#define NW_INP 12     // padded
#define NW_H   16     // u64 words for 1024 hidden bits
#define LSTRIDE 144   // ilist entries per (b,t) row (mult of 8; 70 + 9.3 sigma safe)
#define ZROW_OFF (700*4096)   // byte offset of zero row in Wt_pad

typedef unsigned long long u64;
typedef unsigned int u32;
typedef float vfloat2 __attribute__((ext_vector_type(2)));

// ---------------- prep: transpose weights ----------------
// Wt_pad[704][1024]: rows 0..699 = W_hid^T, rows 700..703 = 0 (pad target).
// WoT_perm[h'][o] with h' = w*64+j decoding hidden_kernel's ballot packing:
//   half=(h'>>9), wv=(h'>>7)&3, k=(h'>>6)&1, j=h'&63  ->  h = half*512+wv*128+2j+k
__global__ void prep_weights(const float* __restrict__ W_hid,
                             const float* __restrict__ W_out,
                             float* __restrict__ Wt,
                             float* __restrict__ WoT) {
    int idx = blockIdx.x * 256 + threadIdx.x;
    if (blockIdx.x < 2816) {                 // 704*1024 = 720896 = 2816*256
        int d = idx >> 10;
        int h = idx & 1023;
        Wt[idx] = (d < DIN) ? W_hid[h * DIN + d] : 0.0f;
    } else {
        int i = idx - 2816 * 256;            // 0..20479
        int hp = i / DOUT;
        int o  = i - hp * DOUT;
        int half = hp >> 9, wv = (hp >> 7) & 3, k = (hp >> 6) & 1, j = hp & 63;
        int h = half * 512 + wv * 128 + 2 * j + k;
        WoT[i] = W_out[o * H + h];
    }
}

// ---------------- prep: bitpack spikes ----------------
__global__ void prep_bits(const float* __restrict__ spk,
                          u64* __restrict__ bits) {
    int b  = blockIdx.x >> 2;
    int wc = blockIdx.x & 3;
    int t  = threadIdx.x;
    if (t >= T) return;
    int w0 = wc * 3;
    int w1 = (wc == 3) ? NW_IN : w0 + 3;
    const float* base = spk + (size_t)b * DIN * T + t;
    for (int w = w0; w < w1; ++w) {
        u64 m = 0;
#pragma unroll
        for (int j = 0; j < 64; ++j) {
            int d = (w << 6) + j;
            if (d < DIN) {
                float x = base[(size_t)d * T];
                m |= (u64)(x > 0.5f) << j;
            }
        }
        bits[((size_t)b * T + t) * NW_INP + w] = m;
    }
}

// ---------------- expand: bits -> padded offset lists ----------------
// one wave per (b,t) row; lane j handles bit j of each word.
// ilist entries are byte offsets d*4096, ascending d; padded to mult of 8
// with ZROW_OFF. ncnt[row] = n (unpadded count).
__global__ void __launch_bounds__(256)
expand_kernel(const u64* __restrict__ bits,
              u32* __restrict__ ilist,
              u32* __restrict__ ncnt) {
    int wv   = threadIdx.x >> 6;
    int lane = threadIdx.x & 63;
    int row  = blockIdx.x * 4 + wv;          // 16000 blocks -> 64000 rows
    const u64* wp = bits + (size_t)row * NW_INP;
    u32* lp = ilist + (size_t)row * LSTRIDE;

    u64 lmask = (lane == 63) ? 0x7fffffffffffffffull : ((1ull << lane) - 1ull);
    u32 base = 0;
#pragma unroll
    for (int w = 0; w < NW_IN; ++w) {
        u64 m = wp[w];
        if ((m >> lane) & 1ull) {
            u32 pos = base + (u32)__popcll(m & lmask);
            if (pos < LSTRIDE) lp[pos] = ((u32)w << 18) | ((u32)lane << 12);
        }
        base += (u32)__popcll(m);
    }
    u32 n = base < LSTRIDE ? base : LSTRIDE;
    u32 npad = (n + 7u) & ~7u;
    u32 pos = n + lane;
    if (pos < npad && pos < LSTRIDE) lp[pos] = ZROW_OFF;
    if (lane == 0) ncnt[row] = n;
}

// ---------------- hidden layer: list gather + scan, no barriers ----------------
// grid 512 = (b, half); thread covers h = half*512 + wv*128 + lane*2 + {0,1}.
// Ballot word layout: word w = half*8 + wv*2 + k, bit j -> h = base+2j+k
// (compensated by WoT_perm in prep_weights).
__global__ void __launch_bounds__(256)
hidden_kernel(const u32* __restrict__ ilist,
              const u32* __restrict__ ncnt,
              const float* __restrict__ Wt,
              const float* __restrict__ hs0,
              const float* __restrict__ hv0,
              u64* __restrict__ hsbits) {
    int blk  = blockIdx.x;
    int b    = blk >> 1;
    int half = blk & 1;
    int tid  = threadIdx.x;
    int wv   = tid >> 6;
    int lane = tid & 63;
    int h    = (half << 9) + (wv << 7) + (lane << 1);

    const char* Wtb = (const char*)Wt + h * 4;   // fold h-byte into base

    vfloat2 hv0v = *(const vfloat2*)(hv0 + b * H + h);
    vfloat2 hs0v = *(const vfloat2*)(hs0 + b * H + h);
    float keep0 = hv0v.x * 0.5f * (1.0f - hs0v.x);
    float keep1 = hv0v.y * 0.5f * (1.0f - hs0v.y);

    const u32* lrow = ilist + (size_t)(b * T) * LSTRIDE;
    const u32* crow = ncnt + b * T;
    u64* hrow = hsbits + (size_t)(b * T) * NW_H + (half << 3) + (wv << 1);

    for (int t = 0; t < T; ++t) {
        int n = crow[t];
        const u32* lp = lrow + t * LSTRIDE;
        int m = (n + 7) >> 3;
        vfloat2 acc = {0.0f, 0.0f};
        for (int c = 0; c < m; ++c) {
            uint4 oA = *(const uint4*)(lp);
            uint4 oB = *(const uint4*)(lp + 4);
            lp += 8;
            vfloat2 v0 = *(const vfloat2*)(Wtb + oA.x);
            vfloat2 v1 = *(const vfloat2*)(Wtb + oA.y);
            vfloat2 v2 = *(const vfloat2*)(Wtb + oA.z);
            vfloat2 v3 = *(const vfloat2*)(Wtb + oA.w);
            vfloat2 v4 = *(const vfloat2*)(Wtb + oB.x);
            vfloat2 v5 = *(const vfloat2*)(Wtb + oB.y);
            vfloat2 v6 = *(const vfloat2*)(Wtb + oB.z);
            vfloat2 v7 = *(const vfloat2*)(Wtb + oB.w);
            acc += v0; acc += v1; acc += v2; acc += v3;
            acc += v4; acc += v5; acc += v6; acc += v7;
        }
        float hva = keep0 + acc.x;
        float hvb = keep1 + acc.y;
        bool s0 = hva > 0.5f;
        bool s1 = hvb > 0.5f;
        keep0 = s0 ? 0.0f : hva * 0.5f;
        keep1 = s1 ? 0.0f : hvb * 0.5f;
        u64 b0 = __ballot(s0);
        u64 b1 = __ballot(s1);
        if (lane == 0) {
            hrow[0] = b0;
            hrow[1] = b1;
        }
        hrow += NW_H;
    }
}

// ---------------- output currents: Iout[b*T+t][o] ----------------
// one wave per row (b,t); WoT is pre-permuted so index w*64+j is direct.
__global__ void __launch_bounds__(256)
out_currents(const u64* __restrict__ hsbits,
             const float* __restrict__ WoT,
             float* __restrict__ Iout) {
    __shared__ int lidx[4][2][256];

    int wv   = threadIdx.x >> 6;
    int lane = threadIdx.x & 63;
    int row  = blockIdx.x * 4 + wv;   // < 64000 exactly

    const u64* wp = hsbits + (size_t)row * NW_H;

    float acc = 0.0f;
#pragma unroll
    for (int g = 0; g < 4; ++g) {
        u64 w[4];
#pragma unroll
        for (int k = 0; k < 4; ++k) w[k] = wp[g * 4 + k];

        int base[5];
        base[0] = 0;
#pragma unroll
        for (int k = 0; k < 4; ++k) base[k + 1] = base[k] + __popcll(w[k]);
        int n = base[4];

        int buf = g & 1;
#pragma unroll
        for (int k = 0; k < 4; ++k) {
            u64 m = w[k];
            if ((m >> lane) & 1ull) {
                int pos = base[k] + __popcll(m & ((lane == 63) ? 0x7fffffffffffffffull
                                                               : ((1ull << lane) - 1ull)));
                lidx[wv][buf][pos] = ((g * 4 + k) << 6) + lane;
            }
        }
        __syncthreads();

        const int* il = lidx[wv][buf];
        int i = 0;
        for (; i + 4 <= n; i += 4) {
            int j0 = il[i + 0], j1 = il[i + 1], j2 = il[i + 2], j3 = il[i + 3];
            if (lane < DOUT) {
                float v0 = WoT[(size_t)j0 * DOUT + lane];
                float v1 = WoT[(size_t)j1 * DOUT + lane];
                float v2 = WoT[(size_t)j2 * DOUT + lane];
                float v3 = WoT[(size_t)j3 * DOUT + lane];
                acc += v0; acc += v1; acc += v2; acc += v3;
            }
        }
        for (; i < n; ++i) {
            if (lane < DOUT) acc += WoT[(size_t)il[i] * DOUT + lane];
        }
    }
    if (lane < DOUT) Iout[(size_t)row * DOUT + lane] = acc;
}

// ---------------- output scan + spike count ----------------
__global__ void out_scan(const float* __restrict__ Iout,
                         const float* __restrict__ os0,
                         const float* __restrict__ ov0,
                         float* __restrict__ outp) {
    int idx = blockIdx.x * 256 + threadIdx.x;
    if (idx >= B * DOUT) return;
    int b = idx / DOUT;
    int o = idx - b * DOUT;

    float ov = ov0[idx];
    float os = os0[idx];
    float keep = ov * 0.5f * (1.0f - os);
    float cnt = 0.0f;
    const float* ip = Iout + (size_t)b * T * DOUT + o;
#pragma unroll 5
    for (int t = 0; t < T; ++t) {
        float v = keep + ip[(size_t)t * DOUT];
        float s = (v > 0.5f) ? 1.0f : 0.0f;
        cnt += s;
        keep = v * 0.5f * (1.0f - s);
    }
    outp[idx] = cnt;
}

extern "C" void kernel_launch(void* const* d_in, const int* in_sizes, int n_in,
                              void* d_out, int out_size, void* d_ws, size_t ws_size,
                              hipStream_t stream) {
    const float* spike = (const float*)d_in[0];   // [256][700][250]
    const float* W_hid = (const float*)d_in[1];   // [1024][700]
    const float* W_out = (const float*)d_in[2];   // [20][1024]
    const float* hs0   = (const float*)d_in[3];   // [256][1024]
    const float* hv0   = (const float*)d_in[4];
    const float* os0   = (const float*)d_in[5];   // [256][20]
    const float* ov0   = (const float*)d_in[6];
    float* outp = (float*)d_out;                  // [256][20]

    char* ws = (char*)d_ws;
    float* Wt     = (float*)(ws);                     // 704*1024*4      = 2,883,584
    float* WoT    = (float*)(ws + 2883584);           // 20480*4         =    81,920
    u64*   bits   = (u64*)  (ws + 2965504);           // 64000*12*8      = 6,144,000
    u32*   ncnt   = (u32*)  (ws + 9109504);           // 64000*4         =   256,000
    u32*   ilist  = (u32*)  (ws + 9365504);           // 64000*144*4     = 36,864,000
    u64*   hsbits = (u64*)  (ws + 46229504);          // 64000*16*8      = 8,192,000
    float* Iout   = (float*)(ws + 54421504);          // 64000*20*4      = 5,120,000
    // total 59,541,504 B

    prep_weights<<<2896, 256, 0, stream>>>(W_hid, W_out, Wt, WoT);
    prep_bits<<<1024, 256, 0, stream>>>(spike, bits);
    expand_kernel<<<16000, 256, 0, stream>>>(bits, ilist, ncnt);
    hidden_kernel<<<512, 256, 0, stream>>>(ilist, ncnt, Wt, hs0, hv0, hsbits);
    out_currents<<<16000, 256, 0, stream>>>(hsbits, WoT, Iout);
    out_scan<<<20, 256, 0, stream>>>(Iout, os0, ov0, outp);
}